// Round 1
// baseline (225.814 us; speedup 1.0000x reference)
//
#include <hip/hip_runtime.h>

typedef __bf16 bf16x4 __attribute__((ext_vector_type(4)));
typedef __bf16 bf16x8 __attribute__((ext_vector_type(8)));
typedef float  f32x4  __attribute__((ext_vector_type(4)));

// One kernel per type. Block = 256 threads = 4 waves.
// Wave w owns output columns [32w, 32w+32). W^T fragments live in registers.
// x rows staged 64 at a time into LDS as bf16 with XOR swizzle (T2).
template<int FIN>
__global__ __launch_bounds__(256) void hetero_lin_kern(
    const float* __restrict__ x, const float* __restrict__ W,
    const float* __restrict__ bias, float* __restrict__ out, int nrows)
{
    __shared__ __bf16 Alds[64 * FIN];

    const int tid  = threadIdx.x;
    const int lane = tid & 63;
    const int wave = tid >> 6;
    const int l15  = lane & 15;
    const int lq   = lane >> 4;       // 0..3 : k-group within fragment

    // ---- W fragments in registers (B operand: B[k][o] = W[o][k], row-major W
    //      gives contiguous k per lane). Converted fp32->bf16 once per block.
    bf16x8 Wf[FIN / 32][2];
    float  bv[2];
    #pragma unroll
    for (int t = 0; t < 2; ++t) {
        const int o = wave * 32 + t * 16 + l15;      // output column (W row)
        bv[t] = bias[o];
        #pragma unroll
        for (int c = 0; c < FIN / 32; ++c) {
            const int k0 = c * 32 + lq * 8;
            const float4 w0 = *(const float4*)(W + (size_t)o * FIN + k0);
            const float4 w1 = *(const float4*)(W + (size_t)o * FIN + k0 + 4);
            bf16x8 f;
            f[0] = (__bf16)w0.x; f[1] = (__bf16)w0.y;
            f[2] = (__bf16)w0.z; f[3] = (__bf16)w0.w;
            f[4] = (__bf16)w1.x; f[5] = (__bf16)w1.y;
            f[6] = (__bf16)w1.z; f[7] = (__bf16)w1.w;
            Wf[c][t] = f;
        }
    }

    const int nchunks = (nrows + 63) >> 6;
    for (int chunk = blockIdx.x; chunk < nchunks; chunk += gridDim.x) {
        const int row0 = chunk * 64;

        __syncthreads();   // previous iteration's readers done before overwrite

        // ---- stage 64 x FIN fp32 -> bf16 into LDS, swizzled.
        // unit = one float4 (16B read, 8B LDS write). Fully coalesced reads.
        #pragma unroll
        for (int u = tid; u < 16 * FIN; u += 256) {   // 64*FIN/4 units
            const int r  = u / (FIN / 4);
            const int kq = u % (FIN / 4);
            int gr = row0 + r;
            if (gr >= nrows) gr = nrows - 1;          // clamp (stores guarded)
            const float4 v = *(const float4*)(x + (size_t)gr * FIN + kq * 4);
            bf16x4 bq;
            bq[0] = (__bf16)v.x; bq[1] = (__bf16)v.y;
            bq[2] = (__bf16)v.z; bq[3] = (__bf16)v.w;
            const int byte = (r * FIN * 2 + kq * 8) ^ ((r & 7) << 4);
            *(bf16x4*)((char*)Alds + byte) = bq;
        }
        __syncthreads();

        // ---- each wave: 4 m-tiles (16 rows) x 2 n-tiles (16 cols)
        #pragma unroll
        for (int mt = 0; mt < 4; ++mt) {
            f32x4 acc0 = {0.f, 0.f, 0.f, 0.f};
            f32x4 acc1 = {0.f, 0.f, 0.f, 0.f};
            const int m = mt * 16 + l15;
            #pragma unroll
            for (int c = 0; c < FIN / 32; ++c) {
                const int k0   = c * 32 + lq * 8;
                const int byte = (m * FIN * 2 + k0 * 2) ^ ((m & 7) << 4);
                const bf16x8 a = *(const bf16x8*)((char*)Alds + byte);
                acc0 = __builtin_amdgcn_mfma_f32_16x16x32_bf16(a, Wf[c][0], acc0, 0, 0, 0);
                acc1 = __builtin_amdgcn_mfma_f32_16x16x32_bf16(a, Wf[c][1], acc1, 0, 0, 0);
            }
            // ---- epilogue: D lane map col=lane&15, row=(lane>>4)*4+r (m89)
            const int colbase = wave * 32;
            #pragma unroll
            for (int r = 0; r < 4; ++r) {
                const int grow = row0 + mt * 16 + lq * 4 + r;
                if (grow < nrows) {
                    out[(size_t)grow * 128 + colbase + l15]      = acc0[r] + bv[0];
                    out[(size_t)grow * 128 + colbase + 16 + l15] = acc1[r] + bv[1];
                }
            }
        }
    }
}

template<int FIN>
static inline void launch_type(const void* x, const void* W, const void* b,
                               float* out, int n, hipStream_t stream)
{
    int blocks = (n + 63) / 64;
    const int cap = (FIN == 256) ? 1280 : 2048;  // LDS-occupancy-aware caps
    if (blocks > cap) blocks = cap;
    hetero_lin_kern<FIN><<<blocks, 256, 0, stream>>>(
        (const float*)x, (const float*)W, (const float*)b, out, n);
}

extern "C" void kernel_launch(void* const* d_in, const int* in_sizes, int n_in,
                              void* d_out, int out_size, void* d_ws, size_t ws_size,
                              hipStream_t stream)
{
    float* out = (float*)d_out;
    // setup_inputs order: (x, W, b) per type:
    // 0 author(n=100000,f=128)  1 paper(250000,256)  2 venue(25000,64)
    // 3 institution(50000,128)  4 field(75000,64)    5 term(150000,128)
    launch_type<128>(d_in[0],  d_in[1],  d_in[2],  out + 0L,        100000, stream);
    launch_type<256>(d_in[3],  d_in[4],  d_in[5],  out + 12800000L, 250000, stream);
    launch_type< 64>(d_in[6],  d_in[7],  d_in[8],  out + 44800000L,  25000, stream);
    launch_type<128>(d_in[9],  d_in[10], d_in[11], out + 48000000L,  50000, stream);
    launch_type< 64>(d_in[12], d_in[13], d_in[14], out + 54400000L,  75000, stream);
    launch_type<128>(d_in[15], d_in[16], d_in[17], out + 64000000L, 150000, stream);
}

// Round 2
// 169.235 us; speedup vs baseline: 1.3343x; 1.3343x over previous
//
#include <hip/hip_runtime.h>

typedef __bf16 bf16x4 __attribute__((ext_vector_type(4)));
typedef __bf16 bf16x8 __attribute__((ext_vector_type(8)));
typedef float  f32x4  __attribute__((ext_vector_type(4)));

struct KArgs {
    const float* x[6];
    const float* W[6];
    const float* b[6];
    float*       out[6];
    int nrows[6];
    int blk0[7];   // cumulative block offsets per type
};

// Process chunks [c0,c1) of one type. Block = 256 threads = 4 waves.
// Operands SWAPPED vs naive: A = W (M axis = output col), B = x (N axis = row).
// -> D lane map: col(l15) = x-row, row(lq*4+r) = output col => float4 stores.
template<int FIN>
__device__ __forceinline__ void run_type(
    const float* __restrict__ x, const float* __restrict__ W,
    const float* __restrict__ bias, float* __restrict__ out,
    int nrows, int c0, int c1, __bf16* __restrict__ Alds)
{
    constexpr int KS    = (FIN < 128) ? FIN : 128;  // K per LDS slab
    constexpr int NSLAB = FIN / KS;
    constexpr int NC    = FIN / 32;                 // k-fragments total
    constexpr int CPS   = KS / 32;                  // k-fragments per slab
    constexpr int UPT   = KS / 16;                  // float4 staging units/thread
    constexpr int BATCH = (UPT > 4) ? 4 : UPT;      // cap in-flight regs

    const int tid  = threadIdx.x;
    const int lane = tid & 63;
    const int wave = tid >> 6;
    const int l15  = lane & 15;
    const int lq   = lane >> 4;

    // ---- W fragments (A operand): lane holds W[o = wave*32+t*16+l15][c*32+lq*8+j]
    bf16x8 Wf[NC][2];
    f32x4  bv[2];
    #pragma unroll
    for (int t = 0; t < 2; ++t) {
        const int o = wave * 32 + t * 16 + l15;
        #pragma unroll
        for (int c = 0; c < NC; ++c) {
            const int k0 = c * 32 + lq * 8;
            const f32x4 w0 = *(const f32x4*)(W + (size_t)o * FIN + k0);
            const f32x4 w1 = *(const f32x4*)(W + (size_t)o * FIN + k0 + 4);
            bf16x8 f;
            f[0] = (__bf16)w0[0]; f[1] = (__bf16)w0[1];
            f[2] = (__bf16)w0[2]; f[3] = (__bf16)w0[3];
            f[4] = (__bf16)w1[0]; f[5] = (__bf16)w1[1];
            f[6] = (__bf16)w1[2]; f[7] = (__bf16)w1[3];
            Wf[c][t] = f;
        }
        // bias for epilogue: lane needs bias[wave*32 + t*16 + lq*4 + r], r=0..3
        bv[t] = *(const f32x4*)(bias + wave * 32 + t * 16 + lq * 4);
    }

    for (int chunk = c0; chunk < c1; ++chunk) {
        const int row0 = chunk * 64;
        f32x4 acc[4][2] = {};

        #pragma unroll
        for (int slab = 0; slab < NSLAB; ++slab) {
            __syncthreads();   // prior readers done before LDS overwrite

            // ---- stage 64 x KS fp32 -> bf16 into LDS, XOR-swizzled (T2)
            #pragma unroll
            for (int b0 = 0; b0 < UPT; b0 += BATCH) {
                f32x4 tmp[BATCH];
                #pragma unroll
                for (int i = 0; i < BATCH; ++i) {
                    const int u  = tid + (b0 + i) * 256;
                    const int r  = u / (KS / 4);
                    const int kq = u % (KS / 4);
                    int gr = row0 + r;
                    if (gr >= nrows) gr = nrows - 1;   // clamp; stores guarded
                    tmp[i] = __builtin_nontemporal_load(
                        (const f32x4*)(x + (size_t)gr * FIN + slab * KS + kq * 4));
                }
                #pragma unroll
                for (int i = 0; i < BATCH; ++i) {
                    const int u  = tid + (b0 + i) * 256;
                    const int r  = u / (KS / 4);
                    const int kq = u % (KS / 4);
                    bf16x4 bq;
                    bq[0] = (__bf16)tmp[i][0]; bq[1] = (__bf16)tmp[i][1];
                    bq[2] = (__bf16)tmp[i][2]; bq[3] = (__bf16)tmp[i][3];
                    const int byte = (r * KS * 2 + kq * 8) ^ ((r & 7) << 4);
                    *(bf16x4*)((char*)Alds + byte) = bq;
                }
            }
            __syncthreads();

            // ---- MFMA: 4 row-tiles x 2 col-tiles, A=W (regs), B=x (LDS)
            #pragma unroll
            for (int nt = 0; nt < 4; ++nt) {
                const int row = nt * 16 + l15;
                #pragma unroll
                for (int c = 0; c < CPS; ++c) {
                    const int byte = (row * KS * 2 + c * 64 + lq * 16) ^ ((row & 7) << 4);
                    const bf16x8 xf = *(const bf16x8*)((char*)Alds + byte);
                    acc[nt][0] = __builtin_amdgcn_mfma_f32_16x16x32_bf16(
                        Wf[slab * CPS + c][0], xf, acc[nt][0], 0, 0, 0);
                    acc[nt][1] = __builtin_amdgcn_mfma_f32_16x16x32_bf16(
                        Wf[slab * CPS + c][1], xf, acc[nt][1], 0, 0, 0);
                }
            }
        }

        // ---- epilogue: lane holds 4 consecutive output cols of one row
        #pragma unroll
        for (int nt = 0; nt < 4; ++nt) {
            const int xrow = row0 + nt * 16 + l15;
            if (xrow < nrows) {
                #pragma unroll
                for (int t = 0; t < 2; ++t) {
                    const f32x4 v = acc[nt][t] + bv[t];
                    __builtin_nontemporal_store(v,
                        (f32x4*)(out + (size_t)xrow * 128 + wave * 32 + t * 16 + lq * 4));
                }
            }
        }
    }
}

__global__ __launch_bounds__(256) void hetero_fused_kern(KArgs A)
{
    __shared__ __bf16 Alds[64 * 128];   // 16 KiB, shared by all FIN paths

    // which type does this block serve?
    int ty = 0;
    const int bid = blockIdx.x;
    while (ty < 5 && bid >= A.blk0[ty + 1]) ++ty;
    const int lb = bid - A.blk0[ty];
    const int nb = A.blk0[ty + 1] - A.blk0[ty];

    const int nrows  = A.nrows[ty];
    const int chunks = (nrows + 63) >> 6;
    const int c0 = (int)(((long)chunks * lb) / nb);
    const int c1 = (int)(((long)chunks * (lb + 1)) / nb);
    if (c0 >= c1) return;

    switch (ty) {
        case 0: run_type<128>(A.x[0], A.W[0], A.b[0], A.out[0], nrows, c0, c1, Alds); break;
        case 1: run_type<256>(A.x[1], A.W[1], A.b[1], A.out[1], nrows, c0, c1, Alds); break;
        case 2: run_type< 64>(A.x[2], A.W[2], A.b[2], A.out[2], nrows, c0, c1, Alds); break;
        case 3: run_type<128>(A.x[3], A.W[3], A.b[3], A.out[3], nrows, c0, c1, Alds); break;
        case 4: run_type< 64>(A.x[4], A.W[4], A.b[4], A.out[4], nrows, c0, c1, Alds); break;
        case 5: run_type<128>(A.x[5], A.W[5], A.b[5], A.out[5], nrows, c0, c1, Alds); break;
    }
}

extern "C" void kernel_launch(void* const* d_in, const int* in_sizes, int n_in,
                              void* d_out, int out_size, void* d_ws, size_t ws_size,
                              hipStream_t stream)
{
    float* out = (float*)d_out;
    KArgs A;
    // setup_inputs order: (x,W,b) per type:
    // 0 author(100000,128) 1 paper(250000,256) 2 venue(25000,64)
    // 3 institution(50000,128) 4 field(75000,64) 5 term(150000,128)
    const int   nrows[6] = {100000, 250000, 25000, 50000, 75000, 150000};
    const long  ooff[6]  = {0L, 12800000L, 44800000L, 48000000L, 54400000L, 64000000L};
    // block partition proportional to HBM bytes per type (sum = 2048):
    // author 273, paper 1024, venue 51, inst 137, field 154, term 409
    const int   blk0[7]  = {0, 273, 1297, 1348, 1485, 1639, 2048};
    for (int t = 0; t < 6; ++t) {
        A.x[t]     = (const float*)d_in[3 * t + 0];
        A.W[t]     = (const float*)d_in[3 * t + 1];
        A.b[t]     = (const float*)d_in[3 * t + 2];
        A.out[t]   = out + ooff[t];
        A.nrows[t] = nrows[t];
    }
    for (int i = 0; i < 7; ++i) A.blk0[i] = blk0[i];

    hetero_fused_kern<<<2048, 256, 0, stream>>>(A);
}